// Round 6
// baseline (795.073 us; speedup 1.0000x reference)
//
#include <hip/hip_runtime.h>
#include <cstdint>
#include <cstddef>

// Problem constants
#define TS     4
#define BNROWS 16384   // B*N = 32*512
#define DIMN   512
#define CIN    1024    // 2*DIM

typedef __attribute__((ext_vector_type(8))) short short8;   // 8 bf16
typedef __attribute__((ext_vector_type(4))) float f32x4;

__device__ __forceinline__ uint16_t f2bf(float f) {
    union { float f; uint32_t u; } x; x.f = f;
    return (uint16_t)((x.u + 0x7FFFu + ((x.u >> 16) & 1u)) >> 16);  // RNE
}
__device__ __forceinline__ float bf2f(uint16_t h) {
    union { uint32_t u; float f; } x; x.u = ((uint32_t)h) << 16;
    return x.f;
}

// -------- Kernel 0: split W (fp32) into bf16 hi/mid, FRAGMENT-MAJOR --------
// Layout: Wt[ks][e][kk]  (ks = k>>5, kk = k&31) -> per-(ks,ni) MFMA B-fragment
// load covers one contiguous aligned 1 KB block (fully coalesced).
__global__ __launch_bounds__(256) void k_wsplit(const float* __restrict__ W,
        uint16_t* __restrict__ Wh, uint16_t* __restrict__ Wm) {
    int i = (blockIdx.x * 256 + threadIdx.x) * 4;   // element idx in row-major W
    int e  = i >> 9;
    int k  = i & 511;
    int ks = k >> 5, kk = k & 31;
    size_t o = ((size_t)((ks << 9) + e) << 5) + kk;   // 4 consecutive kk's
    float4 w4 = *(const float4*)(W + i);
    float wv[4] = {w4.x, w4.y, w4.z, w4.w};
    uint16_t hh[4], mm[4];
#pragma unroll
    for (int j = 0; j < 4; ++j) {
        uint16_t a = f2bf(wv[j]);
        float r = wv[j] - bf2f(a);   // exact (Sterbenz)
        hh[j] = a; mm[j] = f2bf(r);
    }
    *(ushort4*)(Wh + o) = make_ushort4(hh[0], hh[1], hh[2], hh[3]);
    *(ushort4*)(Wm + o) = make_ushort4(mm[0], mm[1], mm[2], mm[3]);
}

// ------------- Kernel 1: LIF1 streaming, A8 in k-XOR byte layout ------------
// A8 layout: row = bn*4 + t (512 B/row); byte k stored at k ^ ((row&7)<<3)
// (XOR on bits 3-5 -> permutes 8B granules within 64B; coalescing-neutral,
//  makes k_gemm's ds_read_b64 fragment reads ~2-way instead of 16-way).
__global__ __launch_bounds__(256) void k_lif1(const float* __restrict__ in,
                                              uint8_t* __restrict__ A8) {
    const int gtid = blockIdx.x * 256 + threadIdx.x;   // 1048576 threads
    const int bn = gtid >> 6;
    const int d0 = (gtid & 63) << 3;                   // 8 d's per thread
    float v[8] = {0.f,0.f,0.f,0.f,0.f,0.f,0.f,0.f};
#pragma unroll
    for (int t = 0; t < TS; ++t) {
        const float4* px = (const float4*)(in + ((size_t)(t * BNROWS + bn)) * CIN + DIMN + d0);
        float4 x0 = px[0], x1 = px[1];
        float xs[8] = {x0.x, x0.y, x0.z, x0.w, x1.x, x1.y, x1.z, x1.w};
        union { uint2 u; uint8_t b[8]; } pk;
#pragma unroll
        for (int j = 0; j < 8; ++j) {
            v[j] = v[j] * 0.5f + xs[j];      // charge (x0.5 exact)
            bool sp = (v[j] >= 1.0f);        // fire
            pk.b[j] = sp ? 1u : 0u;
            v[j] = sp ? 0.0f : v[j];         // hard reset
        }
        const int row = bn * 4 + t;
        *(uint2*)(A8 + (size_t)row * 512 + (d0 ^ ((row & 7) << 3))) = pk.u;
    }
}

// ------ Kernel 2: GEMM (A8 reg-staged to LDS, double bf16) + LIF2 -----------
// Block: 512 threads (8 waves), 16 bn rows (64 GEMM rows) x FULL N=512.
// Prologue: 32KB contiguous reg-staged copy (uint4 load + ds_write_b128,
// fully coalesced; swizzle pre-baked in global layout), one barrier, then a
// barrier-free K-loop + LIF2 -> gbits/bad-list epilogue.
#define DELTA 1e-3f
__global__ __launch_bounds__(512, 4) void k_gemm(
        const uint8_t*  __restrict__ A8,
        const uint16_t* __restrict__ Wh,
        const uint16_t* __restrict__ Wm,
        const float*    __restrict__ bias,
        unsigned short* __restrict__ gbits,
        unsigned int*   __restrict__ counter,
        unsigned int*   __restrict__ list,
        unsigned int    cap) {
    __shared__ __align__(16) uint8_t A_lds[32768];   // linear image of block's A8

    const int tid  = threadIdx.x;
    const int blk  = blockIdx.x;        // 1024 blocks
    const int bn0  = blk * 16;
    const int wv   = tid >> 6;          // 8 waves -> e ranges of 64
    const int lane = tid & 63;
    const int ln   = lane & 15;
    const int quad = lane >> 4;
    const int e_base = wv * 64;

    // ---- stage: 32 KB contiguous copy, 4 x 16B per thread, coalesced ----
    {
        const uint8_t* gsrc = A8 + (size_t)blk * 32768;
        const int toff = tid * 16;
#pragma unroll
        for (int it = 0; it < 4; ++it) {
            const int seg = it * 8192 + toff;
            *(uint4*)(&A_lds[seg]) = *(const uint4*)(gsrc + seg);
        }
    }
    __syncthreads();   // only barrier; A_lds read-only below

    // ---------------- K-loop (double bf16) ----------------------------------
    f32x4 acc[4][4] = {};   // [mi][ni]

#pragma unroll 4
    for (int ks = 0; ks < 16; ++ks) {
        // ---- W loads first (coalesced 1KB fragment-major blocks) ----
        short8 bh[4], bm[4];
#pragma unroll
        for (int ni = 0; ni < 4; ++ni) {
            const size_t off = ((size_t)((ks << 9) + e_base + ni * 16 + ln) << 5) + quad * 8;
            bh[ni] = *(const short8*)(Wh + off);
            bm[ni] = *(const short8*)(Wm + off);
        }
        // ---- A fragments from LDS (XOR layout) + byte->bf16 unpack ----
        const int k0 = ks * 32 + quad * 8;   // byte index within row
        short8 a[4];
#pragma unroll
        for (int mi = 0; mi < 4; ++mi) {
            const int row = mi * 16 + ln;
            union { uint2 u; uint8_t b[8]; } ld;
            ld.u = *(const uint2*)(A_lds + row * 512 + (k0 ^ ((row & 7) << 3)));
#pragma unroll
            for (int j = 0; j < 8; ++j)
                a[mi][j] = ld.b[j] ? (short)0x3F80 : (short)0;   // bf16 1.0/0.0
        }
        // ---- MFMAs ----
#pragma unroll
        for (int ni = 0; ni < 4; ++ni) {
#pragma unroll
            for (int mi = 0; mi < 4; ++mi) {
                acc[mi][ni] = __builtin_amdgcn_mfma_f32_16x16x32_bf16(a[mi], bh[ni], acc[mi][ni], 0, 0, 0);
                acc[mi][ni] = __builtin_amdgcn_mfma_f32_16x16x32_bf16(a[mi], bm[ni], acc[mi][ni], 0, 0, 0);
            }
        }
    }

    // ------------- LIF2 + ballot spikes -> global bitmask -------------------
    // C/D layout 16x16: col = lane&15, row = quad*4 + reg. t = reg, bn = row/4.
#pragma unroll
    for (int ni = 0; ni < 4; ++ni) {
        const int e = e_base + ni * 16 + ln;
        const float be = bias[e];
#pragma unroll
        for (int mi = 0; mi < 4; ++mi) {
            const int bn = bn0 + mi * 4 + quad;
            float v = 0.f;
            bool bad = false;
#pragma unroll
            for (int t = 0; t < TS; ++t) {
                float y = acc[mi][ni][t] + be;      // Linear + bias
                v = v * 0.5f + y;                   // LIF2 charge
                bad = bad || (fabsf(v - 1.0f) < DELTA);
                bool sp = (v >= 1.0f);
                unsigned long long b = __ballot(sp);
                if (ln == 0) {
                    gbits[((size_t)(bn * 4 + t)) * 32 + (wv * 4 + ni)] =
                        (unsigned short)((b >> (quad * 16)) & 0xFFFFull);
                }
                v = sp ? 0.0f : v;                  // hard reset
            }
            if (bad) {
                unsigned idx = atomicAdd(counter, 1u);
                if (idx < cap) list[idx] = ((unsigned)bn << 9) | (unsigned)e;
            }
        }
    }
}

// -------- Kernel 3: streaming gate pass (bits + in outputs-half -> out) -----
__global__ __launch_bounds__(256) void k_gate(
        const float*          __restrict__ in,
        const unsigned short* __restrict__ gbits,
        float*                __restrict__ out) {
    const unsigned gtid = blockIdx.x * 256 + threadIdx.x;   // 0..2097151
    const int bn = (gtid >> 7) & 16383;
    const int c  = gtid & 127;                              // float4 idx in row
    const unsigned gidx = ((unsigned)bn * 4) * 32 + (c >> 2);
    const int sh = (c & 3) * 4;
    const float4* __restrict__ in4  = (const float4*)in;
    float4*       __restrict__ out4 = (float4*)out;
#pragma unroll
    for (int t = 0; t < TS; ++t) {
        const float4 ov = in4[(size_t)(t * BNROWS + bn) * 256 + c];   // outputs half
        const unsigned gb = gbits[gidx + t * 32] >> sh;
        float4 o;
        o.x = (gb & 1u) ? ov.x : 0.0f;
        o.y = (gb & 2u) ? ov.y : 0.0f;
        o.z = (gb & 4u) ? ov.z : 0.0f;
        o.w = (gb & 8u) ? ov.w : 0.0f;
        out4[(size_t)t * 2097152 + gtid] = o;
    }
}

// ------- Kernel 4: bitwise emulation of numpy fp32 einsum + LIF2 ------------
// (A8 reads adjusted for the k-XOR layout; everything else identical)
__global__ __launch_bounds__(256) void k_fix(
        const uint8_t* __restrict__ A8,
        const float*   __restrict__ W,
        const float*   __restrict__ bias,
        const float*   __restrict__ in,
        float*         __restrict__ out,
        const unsigned int* __restrict__ counter,
        const unsigned int* __restrict__ list,
        unsigned int cap) {
    unsigned n = *counter; if (n > cap) n = cap;
    unsigned gtid = blockIdx.x * blockDim.x + threadIdx.x;
    unsigned gsz  = gridDim.x * blockDim.x;
    for (unsigned i = gtid; i < n; i += gsz) {
        unsigned item = list[i];
        int bn = (int)(item >> 9), e = (int)(item & 511u);
        const float* wrow = W + (size_t)e * DIMN;
        float v = 0.f;
        for (int t = 0; t < TS; ++t) {
            const int row = bn * 4 + t;
            const uint8_t* arow = A8 + (size_t)row * 512;
            const int xv = (row & 7) << 3;          // k-XOR layout
            float acc0 = 0.f, acc1 = 0.f, acc2 = 0.f, acc3 = 0.f;
            for (int c = 0; c < 32; ++c) {          // 32 blocks of 16
                const int base = c * 16;
#pragma unroll
                for (int j = 3; j >= 0; --j) {      // chained: j=3,2,1,0
                    const int b4 = base + j * 4;
                    float s0 = arow[(b4 + 0) ^ xv] ? 1.0f : 0.0f;
                    float s1 = arow[(b4 + 1) ^ xv] ? 1.0f : 0.0f;
                    float s2 = arow[(b4 + 2) ^ xv] ? 1.0f : 0.0f;
                    float s3 = arow[(b4 + 3) ^ xv] ? 1.0f : 0.0f;
                    acc0 = fmaf(s0, wrow[b4 + 0], acc0);
                    acc1 = fmaf(s1, wrow[b4 + 1], acc1);
                    acc2 = fmaf(s2, wrow[b4 + 2], acc2);
                    acc3 = fmaf(s3, wrow[b4 + 3], acc3);
                }
            }
            float lo  = acc0 + acc1;                // SSE3 hadd reduce
            float hi  = acc2 + acc3;
            float dot = lo + hi;
            float y = dot + bias[e];
            v = v * 0.5f + y;                        // fp32 chain, x0.5 exact
            bool sp = (v >= 1.0f);
            size_t obase = (size_t)(t * BNROWS + bn);
            out[obase * DIMN + e] = sp ? in[obase * CIN + e] : 0.0f;
            v = sp ? 0.0f : v;
        }
    }
}

extern "C" void kernel_launch(void* const* d_in, const int* in_sizes, int n_in,
                              void* d_out, int out_size, void* d_ws, size_t ws_size,
                              hipStream_t stream) {
    const float* in   = (const float*)d_in[0];   // [4,32,512,1024]
    const float* W    = (const float*)d_in[1];   // [512,512]
    const float* bias = (const float*)d_in[2];   // [512]
    float* out = (float*)d_out;                  // [4,32,512,512]

    // ws layout (total ~39.6 MB, same as round-4 proven footprint):
    // A8 32MB | Wh 512K | Wm 512K | counter 64B | list 800K | Gbits 4MB
    uint8_t*        A8      = (uint8_t*)d_ws;
    uint16_t*       Wh      = (uint16_t*)((char*)d_ws + (size_t)33554432);
    uint16_t*       Wm      = (uint16_t*)((char*)d_ws + (size_t)34078720);
    unsigned int*   counter = (unsigned int*)((char*)d_ws + (size_t)34603008);
    unsigned int*   list    = (unsigned int*)((char*)d_ws + (size_t)34603072);
    unsigned short* gbits   = (unsigned short*)((char*)d_ws + (size_t)35403072);
    const unsigned int cap = 200000u;   // expected bad ~20-40K

    hipMemsetAsync(counter, 0, sizeof(unsigned int), stream);
    k_wsplit<<<256, 256, 0, stream>>>(W, Wh, Wm);
    k_lif1<<<4096, 256, 0, stream>>>(in, A8);
    k_gemm<<<1024, 512, 0, stream>>>(A8, Wh, Wm, bias, gbits, counter, list, cap);
    k_gate<<<8192, 256, 0, stream>>>(in, gbits, out);
    k_fix<<<256, 256, 0, stream>>>(A8, W, bias, in, out, counter, list, cap);
}

// Round 7
// 525.927 us; speedup vs baseline: 1.5118x; 1.5118x over previous
//
#include <hip/hip_runtime.h>
#include <cstdint>
#include <cstddef>

// Problem constants
#define TS     4
#define BNROWS 16384   // B*N = 32*512
#define DIMN   512
#define CIN    1024    // 2*DIM

typedef __attribute__((ext_vector_type(8))) short short8;   // 8 bf16
typedef __attribute__((ext_vector_type(4))) float f32x4;

__device__ __forceinline__ uint16_t f2bf(float f) {
    union { float f; uint32_t u; } x; x.f = f;
    return (uint16_t)((x.u + 0x7FFFu + ((x.u >> 16) & 1u)) >> 16);  // RNE
}
__device__ __forceinline__ float bf2f(uint16_t h) {
    union { uint32_t u; float f; } x; x.u = ((uint32_t)h) << 16;
    return x.f;
}

// -------- Kernel 0: split W (fp32) into bf16 hi/mid, FRAGMENT-MAJOR --------
// Layout: Wt[ks][e][kk]  (ks = k>>5, kk = k&31) -> per-(ks,ni) MFMA B-fragment
// load covers one contiguous aligned 1 KB block (fully coalesced).
// Also zeroes the bad-item counter (replaces a hipMemsetAsync dispatch).
__global__ __launch_bounds__(256) void k_wsplit(const float* __restrict__ W,
        uint16_t* __restrict__ Wh, uint16_t* __restrict__ Wm,
        unsigned int* __restrict__ counter) {
    if (blockIdx.x == 0 && threadIdx.x == 0) *counter = 0u;
    int i = (blockIdx.x * 256 + threadIdx.x) * 4;   // element idx in row-major W
    int e  = i >> 9;
    int k  = i & 511;
    int ks = k >> 5, kk = k & 31;
    size_t o = ((size_t)((ks << 9) + e) << 5) + kk;   // 4 consecutive kk's
    float4 w4 = *(const float4*)(W + i);
    float wv[4] = {w4.x, w4.y, w4.z, w4.w};
    uint16_t hh[4], mm[4];
#pragma unroll
    for (int j = 0; j < 4; ++j) {
        uint16_t a = f2bf(wv[j]);
        float r = wv[j] - bf2f(a);   // exact (Sterbenz)
        hh[j] = a; mm[j] = f2bf(r);
    }
    *(ushort4*)(Wh + o) = make_ushort4(hh[0], hh[1], hh[2], hh[3]);
    *(ushort4*)(Wm + o) = make_ushort4(mm[0], mm[1], mm[2], mm[3]);
}

// ---- Kernel 1 (fused): LIF1 -> LDS(bf16) + A8, GEMM(double bf16) + LIF2 ----
// EXACT round-4 structure (proven 165 us). A8 written LINEAR.
#define DELTA 1e-3f
__global__ __launch_bounds__(512, 4) void k_fused(
        const float*    __restrict__ in,
        const uint16_t* __restrict__ Wh,
        const uint16_t* __restrict__ Wm,
        const float*    __restrict__ bias,
        unsigned short* __restrict__ gbits,
        uint8_t*        __restrict__ A8,
        unsigned int*   __restrict__ counter,
        unsigned int*   __restrict__ list,
        unsigned int    cap) {
    __shared__ short A_lds[64 * 512];   // 64 KiB, row = bn_l*4 + t

    const int tid = threadIdx.x;
    const int blk = blockIdx.x;         // 1024 blocks
    const int bn0 = blk * 16;

    // ---------------- Phase 1: LIF1 (2 (bn,d-group) pairs per thread) -------
#pragma unroll
    for (int pp = 0; pp < 2; ++pp) {
        const int p   = tid + pp * 512;   // 0..1023 = 16 bn x 64 d-groups
        const int bnl = p >> 6;
        const int g   = p & 63;
        const int d0  = g << 3;
        const int bng = bn0 + bnl;
        float v[8] = {0.f,0.f,0.f,0.f,0.f,0.f,0.f,0.f};
#pragma unroll
        for (int t = 0; t < TS; ++t) {
            const float4* px = (const float4*)(in + ((size_t)(t * BNROWS + bng)) * CIN + DIMN + d0);
            float4 x0 = px[0], x1 = px[1];
            float xs[8] = {x0.x, x0.y, x0.z, x0.w, x1.x, x1.y, x1.z, x1.w};
            short8 sb;
            union { uint2 u; uint8_t b[8]; } pk;
#pragma unroll
            for (int j = 0; j < 8; ++j) {
                v[j] = v[j] * 0.5f + xs[j];      // charge (x0.5 exact)
                bool sp = (v[j] >= 1.0f);        // fire
                sb[j]   = sp ? (short)0x3F80 : (short)0;   // bf16 1.0/0.0
                pk.b[j] = sp ? 1u : 0u;
                v[j] = sp ? 0.0f : v[j];         // hard reset
            }
            const int row  = (bnl << 2) + t;
            const int boff = row * 1024 + ((d0 * 2) ^ ((row & 7) << 4));  // XOR swizzle
            *(short8*)((char*)A_lds + boff) = sb;
            *(uint2*)(A8 + ((size_t)((bng << 2) + t)) * DIMN + d0) = pk.u;  // LINEAR
        }
    }
    __syncthreads();   // A_lds ready; read-only below (only barrier)

    // ---------------- Phase 2: GEMM (double bf16) ---------------------------
    const int wv   = tid >> 6;          // 8 waves -> e ranges of 64
    const int lane = tid & 63;
    const int ln   = lane & 15;
    const int quad = lane >> 4;
    const int e_base = wv * 64;

    f32x4 acc[4][4] = {};   // [mi][ni]

#pragma unroll 4
    for (int ks = 0; ks < 16; ++ks) {
        // ---- W loads first (coalesced 1KB fragment-major blocks) ----
        short8 bh[4], bm[4];
#pragma unroll
        for (int ni = 0; ni < 4; ++ni) {
            const size_t off = ((size_t)((ks << 9) + e_base + ni * 16 + ln) << 5) + quad * 8;
            bh[ni] = *(const short8*)(Wh + off);
            bm[ni] = *(const short8*)(Wm + off);
        }
        // ---- A fragments from LDS ----
        const int k0 = ks * 32 + quad * 8;
        short8 a[4];
#pragma unroll
        for (int mi = 0; mi < 4; ++mi) {
            const int row  = mi * 16 + ln;
            const int boff = row * 1024 + ((k0 * 2) ^ ((row & 7) << 4));
            a[mi] = *(const short8*)((const char*)A_lds + boff);
        }
        // ---- MFMAs ----
#pragma unroll
        for (int ni = 0; ni < 4; ++ni) {
#pragma unroll
            for (int mi = 0; mi < 4; ++mi) {
                acc[mi][ni] = __builtin_amdgcn_mfma_f32_16x16x32_bf16(a[mi], bh[ni], acc[mi][ni], 0, 0, 0);
                acc[mi][ni] = __builtin_amdgcn_mfma_f32_16x16x32_bf16(a[mi], bm[ni], acc[mi][ni], 0, 0, 0);
            }
        }
    }

    // ------------- Phase 3: LIF2 + ballot spikes -> global bitmask ----------
    // C/D layout 16x16: col = lane&15, row = quad*4 + reg. t = reg, bn = row/4.
#pragma unroll
    for (int ni = 0; ni < 4; ++ni) {
        const int e = e_base + ni * 16 + ln;
        const float be = bias[e];
#pragma unroll
        for (int mi = 0; mi < 4; ++mi) {
            const int bn = bn0 + mi * 4 + quad;
            float v = 0.f;
            bool bad = false;
#pragma unroll
            for (int t = 0; t < TS; ++t) {
                float y = acc[mi][ni][t] + be;      // Linear + bias
                v = v * 0.5f + y;                   // LIF2 charge
                bad = bad || (fabsf(v - 1.0f) < DELTA);
                bool sp = (v >= 1.0f);
                unsigned long long b = __ballot(sp);
                if (ln == 0) {
                    gbits[((size_t)(bn * 4 + t)) * 32 + (wv * 4 + ni)] =
                        (unsigned short)((b >> (quad * 16)) & 0xFFFFull);
                }
                v = sp ? 0.0f : v;                  // hard reset
            }
            if (bad) {
                unsigned idx = atomicAdd(counter, 1u);
                if (idx < cap) list[idx] = ((unsigned)bn << 9) | (unsigned)e;
            }
        }
    }
}

// -------- Kernel 2: streaming gate pass (bits + in outputs-half -> out) -----
__global__ __launch_bounds__(256) void k_gate(
        const float*          __restrict__ in,
        const unsigned short* __restrict__ gbits,
        float*                __restrict__ out) {
    const unsigned gtid = blockIdx.x * 256 + threadIdx.x;   // 0..2097151
    const int bn = (gtid >> 7) & 16383;
    const int c  = gtid & 127;                              // float4 idx in row
    const unsigned gidx = ((unsigned)bn * 4) * 32 + (c >> 2);
    const int sh = (c & 3) * 4;
    const float4* __restrict__ in4  = (const float4*)in;
    float4*       __restrict__ out4 = (float4*)out;
#pragma unroll
    for (int t = 0; t < TS; ++t) {
        const float4 ov = in4[(size_t)(t * BNROWS + bn) * 256 + c];   // outputs half
        const unsigned gb = gbits[gidx + t * 32] >> sh;
        float4 o;
        o.x = (gb & 1u) ? ov.x : 0.0f;
        o.y = (gb & 2u) ? ov.y : 0.0f;
        o.z = (gb & 4u) ? ov.z : 0.0f;
        o.w = (gb & 8u) ? ov.w : 0.0f;
        out4[(size_t)t * 2097152 + gtid] = o;
    }
}

// ------- Kernel 3: bitwise numpy fp32 einsum + LIF2, WAVE-PARALLEL ----------
// Round-7: 16 lanes per bad item = 4 t x 4 SSE-acc chains. Each lane runs one
// acc chain (128 FMAs, exact numpy order); shuffles reproduce the SSE3 hadd
// reduce (acc0+acc1)+(acc2+acc3) and one lane runs the serial v chain.
// n*16 lanes of TLP replaces the old 1-thread-per-item serial crawl (250 us,
// 0.9% occupancy, round-6 top dispatch).
__global__ __launch_bounds__(256) void k_fix(
        const uint8_t* __restrict__ A8,
        const float*   __restrict__ W,
        const float*   __restrict__ bias,
        const float*   __restrict__ in,
        float*         __restrict__ out,
        const unsigned int* __restrict__ counter,
        const unsigned int* __restrict__ list,
        unsigned int cap) {
    unsigned n = *counter; if (n > cap) n = cap;
    if (n == 0) return;
    const int lane = threadIdx.x & 63;
    const int grp  = lane >> 4;          // item slot within wave (4 per wave)
    const int sub  = lane & 15;
    const int ai   = sub & 3;            // acc chain index (SSE lane)
    const int lt   = sub >> 2;           // timestep
    const unsigned wid = blockIdx.x * (blockDim.x >> 6) + (threadIdx.x >> 6);
    const unsigned nw  = gridDim.x * (blockDim.x >> 6);

    for (unsigned it0 = wid * 4; it0 < n; it0 += nw * 4) {
        const unsigned myi   = it0 + grp;
        const bool    active = (myi < n);
        const unsigned item  = list[active ? myi : 0];
        const int bn = (int)(item >> 9), e = (int)(item & 511u);

        const uint4* a4   = (const uint4*)(A8 + (size_t)(bn * 4 + lt) * 512);
        const float* wrow = W + (size_t)e * DIMN;
        const int sh = 8 * ai;
        float acc = 0.f;
#pragma unroll 4
        for (int c = 0; c < 32; ++c) {          // 32 blocks of 16, ascending
            const uint4 blk = a4[c];            // bytes 0/1, one 16B load
            const float* wq = wrow + c * 16 + ai;
            // chained j = 3,2,1,0 (numpy SSE muladd order); bytes are 0/1
            acc = fmaf((float)((blk.w >> sh) & 0xFFu), wq[12], acc);
            acc = fmaf((float)((blk.z >> sh) & 0xFFu), wq[8],  acc);
            acc = fmaf((float)((blk.y >> sh) & 0xFFu), wq[4],  acc);
            acc = fmaf((float)((blk.x >> sh) & 0xFFu), wq[0],  acc);
        }
        // SSE3 hadd reduce: dot = (acc0+acc1) + (acc2+acc3)  (valid on ai==0 lanes)
        const float a1 = __shfl(acc, (lane & 60) | 1);
        const float a2 = __shfl(acc, (lane & 60) | 2);
        const float a3 = __shfl(acc, (lane & 60) | 3);
        const float dot = (acc + a1) + (a2 + a3);
        // gather the 4 timestep dots (from ai==0 lanes of each t-group)
        const float d0 = __shfl(dot, (lane & 48) | 0);
        const float d1 = __shfl(dot, (lane & 48) | 4);
        const float d2 = __shfl(dot, (lane & 48) | 8);
        const float d3 = __shfl(dot, (lane & 48) | 12);
        if (active && sub == 0) {
            const float be = bias[e];
            const float ds[4] = {d0, d1, d2, d3};
            float v = 0.f;
#pragma unroll
            for (int t = 0; t < TS; ++t) {
                const float y = ds[t] + be;
                v = v * 0.5f + y;                // fp32 chain, x0.5 exact
                const bool sp = (v >= 1.0f);
                const size_t ob = (size_t)(t * BNROWS + bn);
                out[ob * DIMN + e] = sp ? in[ob * CIN + e] : 0.0f;
                v = sp ? 0.0f : v;
            }
        }
    }
}

extern "C" void kernel_launch(void* const* d_in, const int* in_sizes, int n_in,
                              void* d_out, int out_size, void* d_ws, size_t ws_size,
                              hipStream_t stream) {
    const float* in   = (const float*)d_in[0];   // [4,32,512,1024]
    const float* W    = (const float*)d_in[1];   // [512,512]
    const float* bias = (const float*)d_in[2];   // [512]
    float* out = (float*)d_out;                  // [4,32,512,512]

    // ws layout (~39.6 MB): A8 32MB | Wh 512K | Wm 512K | counter 64B | list 800K | Gbits 4MB
    uint8_t*        A8      = (uint8_t*)d_ws;
    uint16_t*       Wh      = (uint16_t*)((char*)d_ws + (size_t)33554432);
    uint16_t*       Wm      = (uint16_t*)((char*)d_ws + (size_t)34078720);
    unsigned int*   counter = (unsigned int*)((char*)d_ws + (size_t)34603008);
    unsigned int*   list    = (unsigned int*)((char*)d_ws + (size_t)34603072);
    unsigned short* gbits   = (unsigned short*)((char*)d_ws + (size_t)35403072);
    const unsigned int cap = 200000u;   // expected bad ~20-40K

    k_wsplit<<<256, 256, 0, stream>>>(W, Wh, Wm, counter);
    k_fused<<<1024, 512, 0, stream>>>(in, Wh, Wm, bias, gbits, A8, counter, list, cap);
    k_gate<<<8192, 256, 0, stream>>>(in, gbits, out);
    k_fix<<<1024, 256, 0, stream>>>(A8, W, bias, in, out, counter, list, cap);
}